// Round 8
// baseline (344.374 us; speedup 1.0000x reference)
//
#include <hip/hip_runtime.h>
#include <hip/hip_bf16.h>

static constexpr int N = 100000;
static constexpr int HID = 128;
static constexpr int NB = (N + 255) / 256;  // 391 scan blocks
static constexpr int NPART = 8;             // one partition per XCD (blockIdx%8 round-robin)
static constexpr int PSZ = N / NPART;       // 12500
static constexpr int EPB = 4096;            // edges per kA_scatter block (16/thread)
static constexpr int SUBC = 128;            // sub-blocks per partition in count/fill

typedef short v8s __attribute__((ext_vector_type(8)));
typedef float v4f __attribute__((ext_vector_type(4)));
typedef unsigned short u16x8 __attribute__((ext_vector_type(8)));

// ---------- bf16 helpers (RNE) ----------
static __device__ __forceinline__ unsigned short f2bf(float x) {
  unsigned u = __float_as_uint(x);
  return (unsigned short)((u + 0x7fffu + ((u >> 16) & 1u)) >> 16);
}
static __device__ __forceinline__ float bf2f(unsigned short u) {
  return __uint_as_float(((unsigned)u) << 16);
}

// ---------- One-time weight prep (+ pcur segment-base init in block 0) ----------
__global__ void k_wprep(const float* __restrict__ ws2, const float* __restrict__ wn2,
                        unsigned short* __restrict__ wp, unsigned* __restrict__ pcur, int cap) {
  if (blockIdx.x == 0 && threadIdx.x < NPART) pcur[threadIdx.x] = (unsigned)threadIdx.x * cap;
  int b = blockIdx.x;     // 64 blocks: mat(2) x ks(4) x cf(8)
  int mat = b >> 5;
  int ks = (b >> 3) & 3;
  int cf = b & 7;
  int l = threadIdx.x;    // 64
  const float* W = mat ? wn2 : ws2;
  int col = cf * 16 + (l & 15);
  int k0 = ks * 32 + (l >> 4) * 8;
  u16x8 h8, l8;
#pragma unroll
  for (int i = 0; i < 8; ++i) {
    float w = W[(k0 + i) * 128 + col];
    unsigned short h = f2bf(w);
    h8[i] = h;
    l8[i] = f2bf(w - bf2f(h));
  }
  int fhi = (ks * 4 + mat) * 8 + cf;
  int flo = (ks * 4 + mat + 2) * 8 + cf;
  *reinterpret_cast<u16x8*>(wp + fhi * 512 + l * 8) = h8;
  *reinterpret_cast<u16x8*>(wp + flo * 512 + l * 8) = l8;
}

// ---------- Bucket edges by dst partition: register counting-sort, shfl scan ----------
// packed = (src << 14) | (dst - p*PSZ);  src < 2^17, dst_local < 12500 < 2^14.
__global__ __launch_bounds__(256) void kA_scatter(const int* __restrict__ src,
                                                  const int* __restrict__ dst,
                                                  unsigned* __restrict__ pcur,
                                                  unsigned* __restrict__ bucket, int E) {
  const int t = threadIdx.x;
  const int lane = t & 63, wv = t >> 6;
  const int e0 = blockIdx.x * EPB;
  const int n = min(e0 + EPB, E) - e0;

  unsigned pk[16];
  int pp[16];
  unsigned cnt[8];
#pragma unroll
  for (int q = 0; q < 8; ++q) cnt[q] = 0;

#pragma unroll
  for (int i = 0; i < 16; ++i) {
    int e = t + 256 * i;
    if (e < n) {
      int d = __builtin_nontemporal_load(dst + e0 + e);
      int s = __builtin_nontemporal_load(src + e0 + e);
      int p = d / PSZ;
      pk[i] = ((unsigned)s << 14) | (unsigned)(d - p * PSZ);
      pp[i] = p;
#pragma unroll
      for (int q = 0; q < 8; ++q) cnt[q] += (p == q) ? 1u : 0u;
    } else {
      pp[i] = -1;
      pk[i] = 0;
    }
  }

  // 64-lane exclusive scan per partition (shfl), wave totals to LDS.
  __shared__ unsigned wtot[4][8];
  __shared__ unsigned woff[4][8];
  __shared__ unsigned gb[8];
  unsigned excl[8];
#pragma unroll
  for (int q = 0; q < 8; ++q) {
    unsigned x = cnt[q];
#pragma unroll
    for (int off = 1; off < 64; off <<= 1) {
      unsigned y = __shfl_up(x, off);
      if (lane >= off) x += y;
    }
    excl[q] = x - cnt[q];
    if (lane == 63) wtot[wv][q] = x;
  }
  __syncthreads();
  if (t < 8) {  // one thread per partition: cross-wave scan + global reserve
    int q = t;
    unsigned acc = 0;
#pragma unroll
    for (int w = 0; w < 4; ++w) {
      woff[w][q] = acc;
      acc += wtot[w][q];
    }
    gb[q] = (acc > 0) ? atomicAdd(&pcur[q], acc) : 0u;
  }
  __syncthreads();

  unsigned tb[8];
#pragma unroll
  for (int q = 0; q < 8; ++q) tb[q] = gb[q] + woff[wv][q] + excl[q];

  unsigned run[8];
#pragma unroll
  for (int q = 0; q < 8; ++q) run[q] = 0;
#pragma unroll
  for (int i = 0; i < 16; ++i) {
    int p = pp[i];
    if (p >= 0) {
      unsigned idx = 0;
#pragma unroll
      for (int q = 0; q < 8; ++q)
        if (p == q) {
          idx = tb[q] + run[q];
          run[q] += 1;
        }
      bucket[idx] = pk[i];
    }
  }
}

// ---------- Per-partition degree count (L2-local bucket read + cnt atomics) ----------
__global__ void kB_count(const unsigned* __restrict__ pcur, const unsigned* __restrict__ bucket,
                         unsigned* __restrict__ cnt, int cap) {
  int p = blockIdx.x & (NPART - 1);
  int sub = blockIdx.x >> 3;
  unsigned b0 = (unsigned)p * cap;
  unsigned sz = pcur[p] - b0;
  unsigned s0 = b0 + (unsigned)(((unsigned long long)sz * sub) / SUBC);
  unsigned s1 = b0 + (unsigned)(((unsigned long long)sz * (sub + 1)) / SUBC);
  int lo = p * PSZ;
  for (unsigned i = s0 + threadIdx.x; i < s1; i += 256)
    atomicAdd(&cnt[lo + (bucket[i] & 16383u)], 1u);
}

// ---------- Scan over node counts ----------
__global__ void k_blocksum(const unsigned* __restrict__ cnt, unsigned* __restrict__ bs) {
  __shared__ unsigned s[256];
  int i = blockIdx.x * 256 + threadIdx.x;
  s[threadIdx.x] = (i < N) ? cnt[i] : 0u;
  __syncthreads();
  for (int off = 128; off > 0; off >>= 1) {
    if (threadIdx.x < off) s[threadIdx.x] += s[threadIdx.x + off];
    __syncthreads();
  }
  if (threadIdx.x == 0) bs[blockIdx.x] = s[0];
}

__global__ void k_scanbs(const unsigned* __restrict__ bs, unsigned* __restrict__ bsoff) {
  __shared__ unsigned s[512];
  int t = threadIdx.x;
  unsigned v = (t < NB) ? bs[t] : 0u;
  s[t] = v;
  __syncthreads();
  for (int off = 1; off < 512; off <<= 1) {
    unsigned x = (t >= off) ? s[t - off] : 0u;
    __syncthreads();
    s[t] += x;
    __syncthreads();
  }
  if (t < NB) bsoff[t] = s[t] - v;  // exclusive
}

__global__ void k_scatter_off(const unsigned* __restrict__ cnt, const unsigned* __restrict__ bsoff,
                              unsigned* __restrict__ roff) {
  __shared__ unsigned s[256];
  int t = threadIdx.x;
  int i = blockIdx.x * 256 + t;
  unsigned v = (i < N) ? cnt[i] : 0u;
  s[t] = v;
  __syncthreads();
  for (int off = 1; off < 256; off <<= 1) {
    unsigned x = (t >= off) ? s[t - off] : 0u;
    __syncthreads();
    s[t] += x;
    __syncthreads();
  }
  if (i < N) roff[i] = bsoff[blockIdx.x] + s[t] - v;  // exclusive prefix
}

// ---------- Per-partition CSR fill (everything L2-local: 800KB bucket + 800KB csr window) ----------
// After this, roff[v] is the INCLUSIVE end of row v; start = roff[v]-cnt[v].
__global__ void kD_fill(const unsigned* __restrict__ pcur, const unsigned* __restrict__ bucket,
                        unsigned* __restrict__ roff, int* __restrict__ csr, int cap) {
  int p = blockIdx.x & (NPART - 1);
  int sub = blockIdx.x >> 3;
  unsigned b0 = (unsigned)p * cap;
  unsigned sz = pcur[p] - b0;
  unsigned s0 = b0 + (unsigned)(((unsigned long long)sz * sub) / SUBC);
  unsigned s1 = b0 + (unsigned)(((unsigned long long)sz * (sub + 1)) / SUBC);
  int lo = p * PSZ;
  for (unsigned i = s0 + threadIdx.x; i < s1; i += 256) {
    unsigned pk = bucket[i];
    unsigned pos = atomicAdd(&roff[lo + (pk & 16383u)], 1u);
    csr[pos] = (int)(pk >> 14);
  }
}

// ---------- Layer 1 fused: gather feats + mean + dense(4->128) + relu -> h1 (bf16) ----------
__global__ void k_layer1(const float* __restrict__ feats, const unsigned* __restrict__ cnt,
                         const unsigned* __restrict__ roff, const int* __restrict__ csr,
                         const float* __restrict__ ws1, const float* __restrict__ wn1,
                         const float* __restrict__ b1, unsigned short* __restrict__ h1) {
  int v = blockIdx.x * 4 + (threadIdx.x >> 6);  // one wave per node
  int l = threadIdx.x & 63;
  if (v >= N) return;
  unsigned c = cnt[v];
  unsigned start = roff[v] - c;
  float4 acc = make_float4(0.f, 0.f, 0.f, 0.f);
  for (unsigned e = l; e < c; e += 64) {
    int s = csr[start + e];
    float4 f = *reinterpret_cast<const float4*>(feats + 4 * s);
    acc.x += f.x; acc.y += f.y; acc.z += f.z; acc.w += f.w;
  }
#pragma unroll
  for (int off = 32; off > 0; off >>= 1) {
    acc.x += __shfl_xor(acc.x, off);
    acc.y += __shfl_xor(acc.y, off);
    acc.z += __shfl_xor(acc.z, off);
    acc.w += __shfl_xor(acc.w, off);
  }
  float inv = 1.0f / fmaxf((float)c, 1.0f);
  float m0 = acc.x * inv, m1 = acc.y * inv, m2 = acc.z * inv, m3 = acc.w * inv;
  float4 fv = *reinterpret_cast<const float4*>(feats + 4 * v);
  unsigned pack = 0;
#pragma unroll
  for (int jj = 0; jj < 2; ++jj) {
    int j = 2 * l + jj;
    float o = b1[j];
    o += fv.x * ws1[j] + fv.y * ws1[128 + j] + fv.z * ws1[256 + j] + fv.w * ws1[384 + j];
    o += m0 * wn1[j] + m1 * wn1[128 + j] + m2 * wn1[256 + j] + m3 * wn1[384 + j];
    o = fmaxf(o, 0.f);
    pack |= ((unsigned)f2bf(o)) << (16 * jj);
  }
  *reinterpret_cast<unsigned*>(h1 + v * HID + 2 * l) = pack;
}

// ---------- 128-dim mean aggregation: one wave per node, 8-deep MLP, no atomics ----------
__global__ void k_agg(const unsigned* __restrict__ cnt, const unsigned* __restrict__ roff,
                      const int* __restrict__ csr, const unsigned short* __restrict__ h1,
                      unsigned short* __restrict__ mean) {
  int v = blockIdx.x * 4 + (threadIdx.x >> 6);
  int l = threadIdx.x & 63;
  if (v >= N) return;
  unsigned c = cnt[v];
  unsigned start = roff[v] - c;
  float x0 = 0.f, x1 = 0.f, y0 = 0.f, y1 = 0.f;
  unsigned e = 0;
  for (; e + 8 <= c; e += 8) {
    int ss[8];
#pragma unroll
    for (int q = 0; q < 8; ++q) ss[q] = csr[start + e + q];
    unsigned pk[8];
#pragma unroll
    for (int q = 0; q < 8; ++q)
      pk[q] = *reinterpret_cast<const unsigned*>(h1 + (size_t)ss[q] * HID + 2 * l);
#pragma unroll
    for (int q = 0; q < 8; q += 2) {
      x0 += bf2f((unsigned short)(pk[q] & 0xffffu)) + bf2f((unsigned short)(pk[q + 1] & 0xffffu));
      x1 += bf2f((unsigned short)(pk[q] >> 16)) + bf2f((unsigned short)(pk[q + 1] >> 16));
    }
  }
  for (; e + 4 <= c; e += 4) {
    int s0 = csr[start + e + 0];
    int s1 = csr[start + e + 1];
    int s2 = csr[start + e + 2];
    int s3 = csr[start + e + 3];
    unsigned p0 = *reinterpret_cast<const unsigned*>(h1 + (size_t)s0 * HID + 2 * l);
    unsigned p1 = *reinterpret_cast<const unsigned*>(h1 + (size_t)s1 * HID + 2 * l);
    unsigned p2 = *reinterpret_cast<const unsigned*>(h1 + (size_t)s2 * HID + 2 * l);
    unsigned p3 = *reinterpret_cast<const unsigned*>(h1 + (size_t)s3 * HID + 2 * l);
    x0 += bf2f((unsigned short)(p0 & 0xffffu)) + bf2f((unsigned short)(p1 & 0xffffu));
    x1 += bf2f((unsigned short)(p0 >> 16)) + bf2f((unsigned short)(p1 >> 16));
    y0 += bf2f((unsigned short)(p2 & 0xffffu)) + bf2f((unsigned short)(p3 & 0xffffu));
    y1 += bf2f((unsigned short)(p2 >> 16)) + bf2f((unsigned short)(p3 >> 16));
  }
  for (; e < c; ++e) {
    int s = csr[start + e];
    unsigned pk = *reinterpret_cast<const unsigned*>(h1 + (size_t)s * HID + 2 * l);
    x0 += bf2f((unsigned short)(pk & 0xffffu));
    x1 += bf2f((unsigned short)(pk >> 16));
  }
  float a0 = x0 + y0, a1 = x1 + y1;
  float inv = 1.0f / fmaxf((float)c, 1.0f);
  unsigned pack = (unsigned)f2bf(a0 * inv) | (((unsigned)f2bf(a1 * inv)) << 16);
  *reinterpret_cast<unsigned*>(mean + (size_t)v * HID + 2 * l) = pack;
}

// ---------- Layer 2 + head via bf16 MFMA (split-bf16 weights). ----------
__global__ __launch_bounds__(256) void k_l2_mfma(
    const unsigned short* __restrict__ h1, const unsigned short* __restrict__ mean,
    const unsigned short* __restrict__ wp, const float* __restrict__ b2,
    const float* __restrict__ wout, const float* __restrict__ bout,
    float* __restrict__ out) {
  const int l = threadIdx.x & 63;
  const int wv = threadIdx.x >> 6;
  const size_t vbase = (size_t)blockIdx.x * 256 + (size_t)wv * 64;
  const int rlane = l & 15;
  const int kg = l >> 4;

  v4f acc[4][8];
#pragma unroll
  for (int rf = 0; rf < 4; ++rf)
#pragma unroll
    for (int cf = 0; cf < 8; ++cf) acc[rf][cf] = (v4f)(0.f);

#pragma unroll
  for (int ks = 0; ks < 4; ++ks) {
    v8s ah[4], am[4];
#pragma unroll
    for (int rf = 0; rf < 4; ++rf) {
      size_t row = vbase + rf * 16 + rlane;
      if (row >= N) row = N - 1;  // tail clamp (store is guarded)
      size_t off = row * HID + ks * 32 + kg * 8;
      ah[rf] = *reinterpret_cast<const v8s*>(h1 + off);
      am[rf] = *reinterpret_cast<const v8s*>(mean + off);
    }
#pragma unroll
    for (int m = 0; m < 4; ++m) {  // Ws_hi, Wn_hi, Ws_lo, Wn_lo
#pragma unroll
      for (int cf = 0; cf < 8; ++cf) {
        v8s bf = *reinterpret_cast<const v8s*>(wp + ((ks * 4 + m) * 8 + cf) * 512 + l * 8);
#pragma unroll
        for (int rf = 0; rf < 4; ++rf) {
          acc[rf][cf] = __builtin_amdgcn_mfma_f32_16x16x32_bf16(
              (m & 1) ? am[rf] : ah[rf], bf, acc[rf][cf], 0, 0, 0);
        }
      }
    }
  }

  // Epilogue: h2 = relu(acc + b2), head out = h2 @ wout + bout.
  float b2c[8], w0c[8], w1c[8];
#pragma unroll
  for (int cf = 0; cf < 8; ++cf) {
    int col = cf * 16 + rlane;
    b2c[cf] = b2[col];
    w0c[cf] = wout[col * 2 + 0];
    w1c[cf] = wout[col * 2 + 1];
  }
  const float bo0 = bout[0], bo1 = bout[1];
#pragma unroll
  for (int rf = 0; rf < 4; ++rf) {
#pragma unroll
    for (int j = 0; j < 4; ++j) {
      float s0 = 0.f, s1 = 0.f;
#pragma unroll
      for (int cf = 0; cf < 8; ++cf) {
        float h2 = fmaxf(acc[rf][cf][j] + b2c[cf], 0.f);
        s0 += h2 * w0c[cf];
        s1 += h2 * w1c[cf];
      }
#pragma unroll
      for (int off = 1; off < 16; off <<= 1) {
        s0 += __shfl_xor(s0, off);
        s1 += __shfl_xor(s1, off);
      }
      size_t row = vbase + rf * 16 + kg * 4 + j;
      if (row < N) {
        if (rlane == 0) out[row * 2 + 0] = s0 + bo0;
        if (rlane == 1) out[row * 2 + 1] = s1 + bo1;
      }
    }
  }
}

extern "C" void kernel_launch(void* const* d_in, const int* in_sizes, int n_in,
                              void* d_out, int out_size, void* d_ws, size_t ws_size,
                              hipStream_t stream) {
  const float* feats = (const float*)d_in[0];
  const int* src = (const int*)d_in[1];
  const int* dst = (const int*)d_in[2];
  const float* ws1 = (const float*)d_in[3];
  const float* wn1 = (const float*)d_in[4];
  const float* b1 = (const float*)d_in[5];
  const float* ws2 = (const float*)d_in[6];
  const float* wn2 = (const float*)d_in[7];
  const float* b2 = (const float*)d_in[8];
  const float* wout = (const float*)d_in[9];
  const float* bout = (const float*)d_in[10];
  float* out = (float*)d_out;
  const int E = in_sizes[1];
  const int cap = E / NPART + E / NPART / 8 + 256;  // 72-sigma slack for binomial partition sizes

  // Workspace layout (16B-aligned):
  char* p = (char*)d_ws;
  unsigned* cnt = (unsigned*)p;              p += (size_t)N * 4;
  unsigned* roff = (unsigned*)p;             p += (size_t)N * 4;
  unsigned* pcur = (unsigned*)p;             p += 16 * 4;
  unsigned* bs = (unsigned*)p;               p += 512 * 4;
  unsigned* bsoff = (unsigned*)p;            p += 512 * 4;
  unsigned* bucket = (unsigned*)p;           p += (size_t)cap * NPART * 4;
  int* csr = (int*)p;                        p += (size_t)E * 4;
  unsigned short* h1 = (unsigned short*)p;   p += (size_t)N * HID * 2;
  unsigned short* mean = (unsigned short*)p; p += (size_t)N * HID * 2;
  unsigned short* wp = (unsigned short*)p;   // 4*128*128 bf16 = 128KB

  hipMemsetAsync(cnt, 0, (size_t)N * 4, stream);

  int nA = (E + EPB - 1) / EPB;
  k_wprep<<<64, 64, 0, stream>>>(ws2, wn2, wp, pcur, cap);
  kA_scatter<<<nA, 256, 0, stream>>>(src, dst, pcur, bucket, E);
  kB_count<<<NPART * SUBC, 256, 0, stream>>>(pcur, bucket, cnt, cap);
  k_blocksum<<<NB, 256, 0, stream>>>(cnt, bs);
  k_scanbs<<<1, 512, 0, stream>>>(bs, bsoff);
  k_scatter_off<<<NB, 256, 0, stream>>>(cnt, bsoff, roff);
  kD_fill<<<NPART * SUBC, 256, 0, stream>>>(pcur, bucket, roff, csr, cap);
  k_layer1<<<N / 4, 256, 0, stream>>>(feats, cnt, roff, csr, ws1, wn1, b1, h1);
  k_agg<<<N / 4, 256, 0, stream>>>(cnt, roff, csr, h1, mean);
  k_l2_mfma<<<(N + 255) / 256, 256, 0, stream>>>(h1, mean, wp, b2, wout, bout, out);
}

// Round 9
// 315.710 us; speedup vs baseline: 1.0908x; 1.0908x over previous
//
#include <hip/hip_runtime.h>
#include <hip/hip_bf16.h>

static constexpr int N = 100000;
static constexpr int HID = 128;
static constexpr int NB = (N + 255) / 256;  // 391 scan blocks
static constexpr int FPART = 4;             // k_fill partitions (best measured: R6)
static constexpr int FSZ = N / FPART;       // 25000

typedef short v8s __attribute__((ext_vector_type(8)));
typedef float v4f __attribute__((ext_vector_type(4)));
typedef unsigned short u16x8 __attribute__((ext_vector_type(8)));

// ---------- bf16 helpers (RNE) ----------
static __device__ __forceinline__ unsigned short f2bf(float x) {
  unsigned u = __float_as_uint(x);
  return (unsigned short)((u + 0x7fffu + ((u >> 16) & 1u)) >> 16);
}
static __device__ __forceinline__ float bf2f(unsigned short u) {
  return __uint_as_float(((unsigned)u) << 16);
}

// ---------- Degree histogram: one pass, NT streaming read ----------
__global__ void k_count(const int* __restrict__ dst, unsigned* __restrict__ cnt, int E) {
  int e = blockIdx.x * 256 + threadIdx.x;
  if (e < E) atomicAdd(&cnt[__builtin_nontemporal_load(dst + e)], 1u);
}

// ---------- Scan over node counts ----------
__global__ void k_blocksum(const unsigned* __restrict__ cnt, unsigned* __restrict__ bs) {
  __shared__ unsigned s[256];
  int i = blockIdx.x * 256 + threadIdx.x;
  s[threadIdx.x] = (i < N) ? cnt[i] : 0u;
  __syncthreads();
  for (int off = 128; off > 0; off >>= 1) {
    if (threadIdx.x < off) s[threadIdx.x] += s[threadIdx.x + off];
    __syncthreads();
  }
  if (threadIdx.x == 0) bs[blockIdx.x] = s[0];
}

__global__ void k_scanbs(const unsigned* __restrict__ bs, unsigned* __restrict__ bsoff) {
  __shared__ unsigned s[512];
  int t = threadIdx.x;
  unsigned v = (t < NB) ? bs[t] : 0u;
  s[t] = v;
  __syncthreads();
  for (int off = 1; off < 512; off <<= 1) {
    unsigned x = (t >= off) ? s[t - off] : 0u;
    __syncthreads();
    s[t] += x;
    __syncthreads();
  }
  if (t < NB) bsoff[t] = s[t] - v;  // exclusive
}

__global__ void k_scatter_off(const unsigned* __restrict__ cnt, const unsigned* __restrict__ bsoff,
                              unsigned* __restrict__ roff) {
  __shared__ unsigned s[256];
  int t = threadIdx.x;
  int i = blockIdx.x * 256 + t;
  unsigned v = (i < N) ? cnt[i] : 0u;
  s[t] = v;
  __syncthreads();
  for (int off = 1; off < 256; off <<= 1) {
    unsigned x = (t >= off) ? s[t - off] : 0u;
    __syncthreads();
    s[t] += x;
    __syncthreads();
  }
  if (i < N) roff[i] = bsoff[blockIdx.x] + s[t] - v;  // exclusive prefix
}

// ---------- CSR fill, partitioned by dst range (R6 best-measured variant) ----------
// After this, roff[v] is the INCLUSIVE end of row v; start = roff[v]-cnt[v].
__global__ void k_fill(const int* __restrict__ src, const int* __restrict__ dst,
                       unsigned* __restrict__ roff, int* __restrict__ csr, int E) {
  int part = blockIdx.x & (FPART - 1);
  int chunk = blockIdx.x >> 2;
  int lo = part * FSZ, hi = lo + FSZ;
  int e0 = chunk * 4096;
  int e1 = min(e0 + 4096, E);
  for (int e = e0 + threadIdx.x; e < e1; e += 256) {
    int d = dst[e];
    if (d >= lo && d < hi) {
      unsigned pos = atomicAdd(&roff[d], 1u);
      csr[pos] = src[e];
    }
  }
}

// ---------- Layer 1 fused: gather feats + mean + dense(4->128) + relu -> h1 (bf16) ----------
__global__ void k_layer1(const float* __restrict__ feats, const unsigned* __restrict__ cnt,
                         const unsigned* __restrict__ roff, const int* __restrict__ csr,
                         const float* __restrict__ ws1, const float* __restrict__ wn1,
                         const float* __restrict__ b1, unsigned short* __restrict__ h1) {
  int v = blockIdx.x * 4 + (threadIdx.x >> 6);  // one wave per node
  int l = threadIdx.x & 63;
  if (v >= N) return;
  unsigned c = cnt[v];
  unsigned start = roff[v] - c;
  float4 acc = make_float4(0.f, 0.f, 0.f, 0.f);
  for (unsigned e = l; e < c; e += 64) {
    int s = csr[start + e];
    float4 f = *reinterpret_cast<const float4*>(feats + 4 * s);
    acc.x += f.x; acc.y += f.y; acc.z += f.z; acc.w += f.w;
  }
#pragma unroll
  for (int off = 32; off > 0; off >>= 1) {
    acc.x += __shfl_xor(acc.x, off);
    acc.y += __shfl_xor(acc.y, off);
    acc.z += __shfl_xor(acc.z, off);
    acc.w += __shfl_xor(acc.w, off);
  }
  float inv = 1.0f / fmaxf((float)c, 1.0f);
  float m0 = acc.x * inv, m1 = acc.y * inv, m2 = acc.z * inv, m3 = acc.w * inv;
  float4 fv = *reinterpret_cast<const float4*>(feats + 4 * v);
  unsigned pack = 0;
#pragma unroll
  for (int jj = 0; jj < 2; ++jj) {
    int j = 2 * l + jj;
    float o = b1[j];
    o += fv.x * ws1[j] + fv.y * ws1[128 + j] + fv.z * ws1[256 + j] + fv.w * ws1[384 + j];
    o += m0 * wn1[j] + m1 * wn1[128 + j] + m2 * wn1[256 + j] + m3 * wn1[384 + j];
    o = fmaxf(o, 0.f);
    pack |= ((unsigned)f2bf(o)) << (16 * jj);
  }
  *reinterpret_cast<unsigned*>(h1 + v * HID + 2 * l) = pack;
}

// ---------- 128-dim mean aggregation: TWO nodes per wave (32 lanes x 8B each), ----------
// ---------- 4-deep unroll -> 8 independent 256B row-gathers in flight per wave ----------
__global__ void k_agg(const unsigned* __restrict__ cnt, const unsigned* __restrict__ roff,
                      const int* __restrict__ csr, const unsigned short* __restrict__ h1,
                      unsigned short* __restrict__ mean, int E) {
  const int wv = threadIdx.x >> 6;
  const int lane = threadIdx.x & 63;
  const int hl = lane & 31;               // lane within half-wave
  const int v = blockIdx.x * 8 + wv * 2 + (lane >> 5);
  if (v >= N) return;                     // N%8==0: never splits a wave in practice
  const unsigned c = cnt[v];
  const unsigned start = roff[v] - c;
  const unsigned cmax = max(c, (unsigned)__shfl_xor((int)c, 32));
  const unsigned short* __restrict__ hrow = h1 + hl * 4;

  float a0 = 0.f, a1 = 0.f, a2 = 0.f, a3 = 0.f;
  float b0 = 0.f, b1 = 0.f, b2 = 0.f, b3 = 0.f;

  for (unsigned e = 0; e < cmax; e += 4) {
    int s[4];
#pragma unroll
    for (int q = 0; q < 4; ++q) {
      unsigned ee = e + q;
      unsigned idx = start + (ee < c ? ee : (c ? c - 1u : 0u));
      idx = min(idx, (unsigned)(E - 1));  // safety clamp for empty trailing rows
      s[q] = csr[idx];
    }
    uint2 pk[4];
#pragma unroll
    for (int q = 0; q < 4; ++q)
      pk[q] = *reinterpret_cast<const uint2*>(hrow + (size_t)s[q] * HID);
#pragma unroll
    for (int q = 0; q < 4; ++q) {
      bool valid = (e + q) < c;
      float f0 = valid ? bf2f((unsigned short)(pk[q].x & 0xffffu)) : 0.f;
      float f1 = valid ? bf2f((unsigned short)(pk[q].x >> 16)) : 0.f;
      float f2 = valid ? bf2f((unsigned short)(pk[q].y & 0xffffu)) : 0.f;
      float f3 = valid ? bf2f((unsigned short)(pk[q].y >> 16)) : 0.f;
      if (q & 1) { b0 += f0; b1 += f1; b2 += f2; b3 += f3; }
      else       { a0 += f0; a1 += f1; a2 += f2; a3 += f3; }
    }
  }
  float inv = 1.0f / fmaxf((float)c, 1.0f);
  a0 = (a0 + b0) * inv; a1 = (a1 + b1) * inv;
  a2 = (a2 + b2) * inv; a3 = (a3 + b3) * inv;
  uint2 o;
  o.x = (unsigned)f2bf(a0) | (((unsigned)f2bf(a1)) << 16);
  o.y = (unsigned)f2bf(a2) | (((unsigned)f2bf(a3)) << 16);
  *reinterpret_cast<uint2*>(mean + (size_t)v * HID + hl * 4) = o;
}

// ---------- One-time weight prep: split-bf16, MFMA-fragment-ordered ----------
__global__ void k_wprep(const float* __restrict__ ws2, const float* __restrict__ wn2,
                        unsigned short* __restrict__ wp) {
  int b = blockIdx.x;     // 64 blocks: mat(2) x ks(4) x cf(8)
  int mat = b >> 5;       // 0: ws2, 1: wn2
  int ks = (b >> 3) & 3;
  int cf = b & 7;
  int l = threadIdx.x;    // 64
  const float* W = mat ? wn2 : ws2;
  int col = cf * 16 + (l & 15);
  int k0 = ks * 32 + (l >> 4) * 8;
  u16x8 h8, l8;
#pragma unroll
  for (int i = 0; i < 8; ++i) {
    float w = W[(k0 + i) * 128 + col];
    unsigned short h = f2bf(w);
    h8[i] = h;
    l8[i] = f2bf(w - bf2f(h));
  }
  int fhi = (ks * 4 + mat) * 8 + cf;
  int flo = (ks * 4 + mat + 2) * 8 + cf;
  *reinterpret_cast<u16x8*>(wp + fhi * 512 + l * 8) = h8;
  *reinterpret_cast<u16x8*>(wp + flo * 512 + l * 8) = l8;
}

// ---------- Layer 2 + head via bf16 MFMA (split-bf16 weights). ----------
__global__ __launch_bounds__(256) void k_l2_mfma(
    const unsigned short* __restrict__ h1, const unsigned short* __restrict__ mean,
    const unsigned short* __restrict__ wp, const float* __restrict__ b2,
    const float* __restrict__ wout, const float* __restrict__ bout,
    float* __restrict__ out) {
  const int l = threadIdx.x & 63;
  const int wv = threadIdx.x >> 6;
  const size_t vbase = (size_t)blockIdx.x * 256 + (size_t)wv * 64;
  const int rlane = l & 15;
  const int kg = l >> 4;

  v4f acc[4][8];
#pragma unroll
  for (int rf = 0; rf < 4; ++rf)
#pragma unroll
    for (int cf = 0; cf < 8; ++cf) acc[rf][cf] = (v4f)(0.f);

#pragma unroll
  for (int ks = 0; ks < 4; ++ks) {
    v8s ah[4], am[4];
#pragma unroll
    for (int rf = 0; rf < 4; ++rf) {
      size_t row = vbase + rf * 16 + rlane;
      if (row >= N) row = N - 1;  // tail clamp (store is guarded)
      size_t off = row * HID + ks * 32 + kg * 8;
      ah[rf] = *reinterpret_cast<const v8s*>(h1 + off);
      am[rf] = *reinterpret_cast<const v8s*>(mean + off);
    }
#pragma unroll
    for (int m = 0; m < 4; ++m) {  // Ws_hi, Wn_hi, Ws_lo, Wn_lo
#pragma unroll
      for (int cf = 0; cf < 8; ++cf) {
        v8s bf = *reinterpret_cast<const v8s*>(wp + ((ks * 4 + m) * 8 + cf) * 512 + l * 8);
#pragma unroll
        for (int rf = 0; rf < 4; ++rf) {
          acc[rf][cf] = __builtin_amdgcn_mfma_f32_16x16x32_bf16(
              (m & 1) ? am[rf] : ah[rf], bf, acc[rf][cf], 0, 0, 0);
        }
      }
    }
  }

  // Epilogue: h2 = relu(acc + b2), head out = h2 @ wout + bout.
  float b2c[8], w0c[8], w1c[8];
#pragma unroll
  for (int cf = 0; cf < 8; ++cf) {
    int col = cf * 16 + rlane;
    b2c[cf] = b2[col];
    w0c[cf] = wout[col * 2 + 0];
    w1c[cf] = wout[col * 2 + 1];
  }
  const float bo0 = bout[0], bo1 = bout[1];
#pragma unroll
  for (int rf = 0; rf < 4; ++rf) {
#pragma unroll
    for (int j = 0; j < 4; ++j) {
      float s0 = 0.f, s1 = 0.f;
#pragma unroll
      for (int cf = 0; cf < 8; ++cf) {
        float h2 = fmaxf(acc[rf][cf][j] + b2c[cf], 0.f);
        s0 += h2 * w0c[cf];
        s1 += h2 * w1c[cf];
      }
#pragma unroll
      for (int off = 1; off < 16; off <<= 1) {
        s0 += __shfl_xor(s0, off);
        s1 += __shfl_xor(s1, off);
      }
      size_t row = vbase + rf * 16 + kg * 4 + j;
      if (row < N) {
        if (rlane == 0) out[row * 2 + 0] = s0 + bo0;
        if (rlane == 1) out[row * 2 + 1] = s1 + bo1;
      }
    }
  }
}

extern "C" void kernel_launch(void* const* d_in, const int* in_sizes, int n_in,
                              void* d_out, int out_size, void* d_ws, size_t ws_size,
                              hipStream_t stream) {
  const float* feats = (const float*)d_in[0];
  const int* src = (const int*)d_in[1];
  const int* dst = (const int*)d_in[2];
  const float* ws1 = (const float*)d_in[3];
  const float* wn1 = (const float*)d_in[4];
  const float* b1 = (const float*)d_in[5];
  const float* ws2 = (const float*)d_in[6];
  const float* wn2 = (const float*)d_in[7];
  const float* b2 = (const float*)d_in[8];
  const float* wout = (const float*)d_in[9];
  const float* bout = (const float*)d_in[10];
  float* out = (float*)d_out;
  const int E = in_sizes[1];

  // Workspace layout (16B-aligned):
  char* p = (char*)d_ws;
  unsigned* cnt = (unsigned*)p;              p += (size_t)N * 4;
  unsigned* roff = (unsigned*)p;             p += (size_t)N * 4;
  unsigned* bs = (unsigned*)p;               p += 512 * 4;
  unsigned* bsoff = (unsigned*)p;            p += 512 * 4;
  int* csr = (int*)p;                        p += (size_t)E * 4;
  unsigned short* h1 = (unsigned short*)p;   p += (size_t)N * HID * 2;
  unsigned short* mean = (unsigned short*)p; p += (size_t)N * HID * 2;
  unsigned short* wp = (unsigned short*)p;   // 4*128*128 bf16 = 128KB

  hipMemsetAsync(cnt, 0, (size_t)N * 4, stream);

  int egrid = (E + 255) / 256;
  int nchunk = (E + 4095) / 4096;
  k_wprep<<<64, 64, 0, stream>>>(ws2, wn2, wp);
  k_count<<<egrid, 256, 0, stream>>>(dst, cnt, E);
  k_blocksum<<<NB, 256, 0, stream>>>(cnt, bs);
  k_scanbs<<<1, 512, 0, stream>>>(bs, bsoff);
  k_scatter_off<<<NB, 256, 0, stream>>>(cnt, bsoff, roff);
  k_fill<<<nchunk * FPART, 256, 0, stream>>>(src, dst, roff, csr, E);
  k_layer1<<<N / 4, 256, 0, stream>>>(feats, cnt, roff, csr, ws1, wn1, b1, h1);
  k_agg<<<(N + 7) / 8, 256, 0, stream>>>(cnt, roff, csr, h1, mean, E);
  k_l2_mfma<<<(N + 255) / 256, 256, 0, stream>>>(h1, mean, wp, b2, wout, bout, out);
}

// Round 10
// 264.717 us; speedup vs baseline: 1.3009x; 1.1926x over previous
//
#include <hip/hip_runtime.h>
#include <hip/hip_bf16.h>

static constexpr int N = 100000;
static constexpr int HID = 128;
static constexpr int NB = (N + 255) / 256;  // 391 scan blocks

typedef short v8s __attribute__((ext_vector_type(8)));
typedef float v4f __attribute__((ext_vector_type(4)));
typedef unsigned short u16x8 __attribute__((ext_vector_type(8)));

// ---------- bf16 helpers (RNE) ----------
static __device__ __forceinline__ unsigned short f2bf(float x) {
  unsigned u = __float_as_uint(x);
  return (unsigned short)((u + 0x7fffu + ((u >> 16) & 1u)) >> 16);
}
static __device__ __forceinline__ float bf2f(unsigned short u) {
  return __uint_as_float(((unsigned)u) << 16);
}

// ---------- Degree histogram + per-edge rank (atomic return value) ----------
__global__ void k_count(const int* __restrict__ dst, unsigned* __restrict__ cnt,
                        unsigned short* __restrict__ rank, int E) {
  int e = blockIdx.x * 256 + threadIdx.x;
  if (e < E) {
    unsigned r = atomicAdd(&cnt[dst[e]], 1u);
    rank[e] = (unsigned short)r;  // rank within dst row; deg >= 65536 impossible here
  }
}

// ---------- Scan over node counts (roff = EXCLUSIVE prefix, never mutated after) ----------
__global__ void k_blocksum(const unsigned* __restrict__ cnt, unsigned* __restrict__ bs) {
  __shared__ unsigned s[256];
  int i = blockIdx.x * 256 + threadIdx.x;
  s[threadIdx.x] = (i < N) ? cnt[i] : 0u;
  __syncthreads();
  for (int off = 128; off > 0; off >>= 1) {
    if (threadIdx.x < off) s[threadIdx.x] += s[threadIdx.x + off];
    __syncthreads();
  }
  if (threadIdx.x == 0) bs[blockIdx.x] = s[0];
}

__global__ void k_scanbs(const unsigned* __restrict__ bs, unsigned* __restrict__ bsoff) {
  __shared__ unsigned s[512];
  int t = threadIdx.x;
  unsigned v = (t < NB) ? bs[t] : 0u;
  s[t] = v;
  __syncthreads();
  for (int off = 1; off < 512; off <<= 1) {
    unsigned x = (t >= off) ? s[t - off] : 0u;
    __syncthreads();
    s[t] += x;
    __syncthreads();
  }
  if (t < NB) bsoff[t] = s[t] - v;  // exclusive
}

__global__ void k_scatter_off(const unsigned* __restrict__ cnt, const unsigned* __restrict__ bsoff,
                              unsigned* __restrict__ roff) {
  __shared__ unsigned s[256];
  int t = threadIdx.x;
  int i = blockIdx.x * 256 + t;
  unsigned v = (i < N) ? cnt[i] : 0u;
  s[t] = v;
  __syncthreads();
  for (int off = 1; off < 256; off <<= 1) {
    unsigned x = (t >= off) ? s[t - off] : 0u;
    __syncthreads();
    s[t] += x;
    __syncthreads();
  }
  if (i < N) roff[i] = bsoff[blockIdx.x] + s[t] - v;  // exclusive prefix
}

// ---------- CSR fill: ATOMIC-FREE scatter via precomputed rank ----------
__global__ void k_fill(const int* __restrict__ src, const int* __restrict__ dst,
                       const unsigned short* __restrict__ rank,
                       const unsigned* __restrict__ roff, int* __restrict__ csr, int E) {
  int stride = gridDim.x * 256;
  for (int e = blockIdx.x * 256 + threadIdx.x; e < E; e += stride) {
    int d = dst[e];
    unsigned pos = roff[d] + (unsigned)rank[e];
    csr[pos] = src[e];
  }
}

// ---------- Layer 1 fused: gather feats + mean + dense(4->128) + relu -> h1 (bf16) ----------
__global__ void k_layer1(const float* __restrict__ feats, const unsigned* __restrict__ cnt,
                         const unsigned* __restrict__ roff, const int* __restrict__ csr,
                         const float* __restrict__ ws1, const float* __restrict__ wn1,
                         const float* __restrict__ b1, unsigned short* __restrict__ h1) {
  int v = blockIdx.x * 4 + (threadIdx.x >> 6);  // one wave per node
  int l = threadIdx.x & 63;
  if (v >= N) return;
  unsigned c = cnt[v];
  unsigned start = roff[v];
  float4 acc = make_float4(0.f, 0.f, 0.f, 0.f);
  for (unsigned e = l; e < c; e += 64) {
    int s = csr[start + e];
    float4 f = *reinterpret_cast<const float4*>(feats + 4 * s);
    acc.x += f.x; acc.y += f.y; acc.z += f.z; acc.w += f.w;
  }
#pragma unroll
  for (int off = 32; off > 0; off >>= 1) {
    acc.x += __shfl_xor(acc.x, off);
    acc.y += __shfl_xor(acc.y, off);
    acc.z += __shfl_xor(acc.z, off);
    acc.w += __shfl_xor(acc.w, off);
  }
  float inv = 1.0f / fmaxf((float)c, 1.0f);
  float m0 = acc.x * inv, m1 = acc.y * inv, m2 = acc.z * inv, m3 = acc.w * inv;
  float4 fv = *reinterpret_cast<const float4*>(feats + 4 * v);
  unsigned pack = 0;
#pragma unroll
  for (int jj = 0; jj < 2; ++jj) {
    int j = 2 * l + jj;
    float o = b1[j];
    o += fv.x * ws1[j] + fv.y * ws1[128 + j] + fv.z * ws1[256 + j] + fv.w * ws1[384 + j];
    o += m0 * wn1[j] + m1 * wn1[128 + j] + m2 * wn1[256 + j] + m3 * wn1[384 + j];
    o = fmaxf(o, 0.f);
    pack |= ((unsigned)f2bf(o)) << (16 * jj);
  }
  *reinterpret_cast<unsigned*>(h1 + v * HID + 2 * l) = pack;
}

// ---------- 128-dim mean aggregation: TWO nodes per wave, 4-deep unroll ----------
__global__ void k_agg(const unsigned* __restrict__ cnt, const unsigned* __restrict__ roff,
                      const int* __restrict__ csr, const unsigned short* __restrict__ h1,
                      unsigned short* __restrict__ mean, int E) {
  const int wv = threadIdx.x >> 6;
  const int lane = threadIdx.x & 63;
  const int hl = lane & 31;               // lane within half-wave
  const int v = blockIdx.x * 8 + wv * 2 + (lane >> 5);
  if (v >= N) return;
  const unsigned c = cnt[v];
  const unsigned start = roff[v];
  const unsigned cmax = max(c, (unsigned)__shfl_xor((int)c, 32));
  const unsigned short* __restrict__ hrow = h1 + hl * 4;

  float a0 = 0.f, a1 = 0.f, a2 = 0.f, a3 = 0.f;
  float b0 = 0.f, b1 = 0.f, b2 = 0.f, b3 = 0.f;

  for (unsigned e = 0; e < cmax; e += 4) {
    int s[4];
#pragma unroll
    for (int q = 0; q < 4; ++q) {
      unsigned ee = e + q;
      unsigned idx = start + (ee < c ? ee : (c ? c - 1u : 0u));
      idx = min(idx, (unsigned)(E - 1));  // safety clamp for empty rows
      s[q] = csr[idx];
    }
    uint2 pk[4];
#pragma unroll
    for (int q = 0; q < 4; ++q)
      pk[q] = *reinterpret_cast<const uint2*>(hrow + (size_t)s[q] * HID);
#pragma unroll
    for (int q = 0; q < 4; ++q) {
      bool valid = (e + q) < c;
      float f0 = valid ? bf2f((unsigned short)(pk[q].x & 0xffffu)) : 0.f;
      float f1 = valid ? bf2f((unsigned short)(pk[q].x >> 16)) : 0.f;
      float f2 = valid ? bf2f((unsigned short)(pk[q].y & 0xffffu)) : 0.f;
      float f3 = valid ? bf2f((unsigned short)(pk[q].y >> 16)) : 0.f;
      if (q & 1) { b0 += f0; b1 += f1; b2 += f2; b3 += f3; }
      else       { a0 += f0; a1 += f1; a2 += f2; a3 += f3; }
    }
  }
  float inv = 1.0f / fmaxf((float)c, 1.0f);
  a0 = (a0 + b0) * inv; a1 = (a1 + b1) * inv;
  a2 = (a2 + b2) * inv; a3 = (a3 + b3) * inv;
  uint2 o;
  o.x = (unsigned)f2bf(a0) | (((unsigned)f2bf(a1)) << 16);
  o.y = (unsigned)f2bf(a2) | (((unsigned)f2bf(a3)) << 16);
  *reinterpret_cast<uint2*>(mean + (size_t)v * HID + hl * 4) = o;
}

// ---------- One-time weight prep: split-bf16, MFMA-fragment-ordered ----------
__global__ void k_wprep(const float* __restrict__ ws2, const float* __restrict__ wn2,
                        unsigned short* __restrict__ wp) {
  int b = blockIdx.x;     // 64 blocks: mat(2) x ks(4) x cf(8)
  int mat = b >> 5;       // 0: ws2, 1: wn2
  int ks = (b >> 3) & 3;
  int cf = b & 7;
  int l = threadIdx.x;    // 64
  const float* W = mat ? wn2 : ws2;
  int col = cf * 16 + (l & 15);
  int k0 = ks * 32 + (l >> 4) * 8;
  u16x8 h8, l8;
#pragma unroll
  for (int i = 0; i < 8; ++i) {
    float w = W[(k0 + i) * 128 + col];
    unsigned short h = f2bf(w);
    h8[i] = h;
    l8[i] = f2bf(w - bf2f(h));
  }
  int fhi = (ks * 4 + mat) * 8 + cf;
  int flo = (ks * 4 + mat + 2) * 8 + cf;
  *reinterpret_cast<u16x8*>(wp + fhi * 512 + l * 8) = h8;
  *reinterpret_cast<u16x8*>(wp + flo * 512 + l * 8) = l8;
}

// ---------- Layer 2 + head via bf16 MFMA (split-bf16 weights). ----------
__global__ __launch_bounds__(256) void k_l2_mfma(
    const unsigned short* __restrict__ h1, const unsigned short* __restrict__ mean,
    const unsigned short* __restrict__ wp, const float* __restrict__ b2,
    const float* __restrict__ wout, const float* __restrict__ bout,
    float* __restrict__ out) {
  const int l = threadIdx.x & 63;
  const int wv = threadIdx.x >> 6;
  const size_t vbase = (size_t)blockIdx.x * 256 + (size_t)wv * 64;
  const int rlane = l & 15;
  const int kg = l >> 4;

  v4f acc[4][8];
#pragma unroll
  for (int rf = 0; rf < 4; ++rf)
#pragma unroll
    for (int cf = 0; cf < 8; ++cf) acc[rf][cf] = (v4f)(0.f);

#pragma unroll
  for (int ks = 0; ks < 4; ++ks) {
    v8s ah[4], am[4];
#pragma unroll
    for (int rf = 0; rf < 4; ++rf) {
      size_t row = vbase + rf * 16 + rlane;
      if (row >= N) row = N - 1;  // tail clamp (store is guarded)
      size_t off = row * HID + ks * 32 + kg * 8;
      ah[rf] = *reinterpret_cast<const v8s*>(h1 + off);
      am[rf] = *reinterpret_cast<const v8s*>(mean + off);
    }
#pragma unroll
    for (int m = 0; m < 4; ++m) {  // Ws_hi, Wn_hi, Ws_lo, Wn_lo
#pragma unroll
      for (int cf = 0; cf < 8; ++cf) {
        v8s bf = *reinterpret_cast<const v8s*>(wp + ((ks * 4 + m) * 8 + cf) * 512 + l * 8);
#pragma unroll
        for (int rf = 0; rf < 4; ++rf) {
          acc[rf][cf] = __builtin_amdgcn_mfma_f32_16x16x32_bf16(
              (m & 1) ? am[rf] : ah[rf], bf, acc[rf][cf], 0, 0, 0);
        }
      }
    }
  }

  // Epilogue: h2 = relu(acc + b2), head out = h2 @ wout + bout.
  float b2c[8], w0c[8], w1c[8];
#pragma unroll
  for (int cf = 0; cf < 8; ++cf) {
    int col = cf * 16 + rlane;
    b2c[cf] = b2[col];
    w0c[cf] = wout[col * 2 + 0];
    w1c[cf] = wout[col * 2 + 1];
  }
  const float bo0 = bout[0], bo1 = bout[1];
#pragma unroll
  for (int rf = 0; rf < 4; ++rf) {
#pragma unroll
    for (int j = 0; j < 4; ++j) {
      float s0 = 0.f, s1 = 0.f;
#pragma unroll
      for (int cf = 0; cf < 8; ++cf) {
        float h2 = fmaxf(acc[rf][cf][j] + b2c[cf], 0.f);
        s0 += h2 * w0c[cf];
        s1 += h2 * w1c[cf];
      }
#pragma unroll
      for (int off = 1; off < 16; off <<= 1) {
        s0 += __shfl_xor(s0, off);
        s1 += __shfl_xor(s1, off);
      }
      size_t row = vbase + rf * 16 + kg * 4 + j;
      if (row < N) {
        if (rlane == 0) out[row * 2 + 0] = s0 + bo0;
        if (rlane == 1) out[row * 2 + 1] = s1 + bo1;
      }
    }
  }
}

extern "C" void kernel_launch(void* const* d_in, const int* in_sizes, int n_in,
                              void* d_out, int out_size, void* d_ws, size_t ws_size,
                              hipStream_t stream) {
  const float* feats = (const float*)d_in[0];
  const int* src = (const int*)d_in[1];
  const int* dst = (const int*)d_in[2];
  const float* ws1 = (const float*)d_in[3];
  const float* wn1 = (const float*)d_in[4];
  const float* b1 = (const float*)d_in[5];
  const float* ws2 = (const float*)d_in[6];
  const float* wn2 = (const float*)d_in[7];
  const float* b2 = (const float*)d_in[8];
  const float* wout = (const float*)d_in[9];
  const float* bout = (const float*)d_in[10];
  float* out = (float*)d_out;
  const int E = in_sizes[1];

  // Workspace layout (16B-aligned):
  char* p = (char*)d_ws;
  unsigned* cnt = (unsigned*)p;              p += (size_t)N * 4;
  unsigned* roff = (unsigned*)p;             p += (size_t)N * 4;
  unsigned* bs = (unsigned*)p;               p += 512 * 4;
  unsigned* bsoff = (unsigned*)p;            p += 512 * 4;
  unsigned short* rank = (unsigned short*)p; p += ((size_t)E * 2 + 15) & ~15ull;
  int* csr = (int*)p;                        p += (size_t)E * 4;
  unsigned short* h1 = (unsigned short*)p;   p += (size_t)N * HID * 2;
  unsigned short* mean = (unsigned short*)p; p += (size_t)N * HID * 2;
  unsigned short* wp = (unsigned short*)p;   // 4*128*128 bf16 = 128KB

  hipMemsetAsync(cnt, 0, (size_t)N * 4, stream);

  int egrid = (E + 255) / 256;
  int fgrid = min(2048, egrid);
  k_wprep<<<64, 64, 0, stream>>>(ws2, wn2, wp);
  k_count<<<egrid, 256, 0, stream>>>(dst, cnt, rank, E);
  k_blocksum<<<NB, 256, 0, stream>>>(cnt, bs);
  k_scanbs<<<1, 512, 0, stream>>>(bs, bsoff);
  k_scatter_off<<<NB, 256, 0, stream>>>(cnt, bsoff, roff);
  k_fill<<<fgrid, 256, 0, stream>>>(src, dst, rank, roff, csr, E);
  k_layer1<<<N / 4, 256, 0, stream>>>(feats, cnt, roff, csr, ws1, wn1, b1, h1);
  k_agg<<<(N + 7) / 8, 256, 0, stream>>>(cnt, roff, csr, h1, mean, E);
  k_l2_mfma<<<(N + 255) / 256, 256, 0, stream>>>(h1, mean, wp, b2, wout, bout, out);
}